// Round 2
// baseline (515.901 us; speedup 1.0000x reference)
//
#include <hip/hip_runtime.h>
#include <hip/hip_bf16.h>
#include <stdint.h>

// B=32, T=512, D=1024, H=16, HD=64
#define NTOK 16384

typedef _Float16 f16;
typedef f16   f16x8 __attribute__((ext_vector_type(8)));
typedef float f32x4 __attribute__((ext_vector_type(4)));

__device__ __forceinline__ float bf2f(ushort h){
  union { uint32_t u; float f; } v; v.u = ((uint32_t)h) << 16; return v.f;
}
__device__ __forceinline__ ushort f2bf(float f){
  union { float f; uint32_t u; } v; v.f = f;
  uint32_t u = v.u;
  return (ushort)((u + 0x7FFFu + ((u >> 16) & 1u)) >> 16);  // RNE
}
__device__ __forceinline__ ushort f2h(float f){          // fp32 -> fp16 bits (RNE)
  return __builtin_bit_cast(ushort, (f16)f);
}
__device__ __forceinline__ f16x8 ld16(const ushort* p){  // 8 fp16
  uint4 u = *(const uint4*)p;
  return __builtin_bit_cast(f16x8, u);
}
// dtype-flexible fp32 load: fp32 path direct, bf16 path converts
__device__ __forceinline__ float ldf(const void* p, size_t idx, int isf32){
  if (isf32) return ((const float*)p)[idx];
  return bf2f(((const ushort*)p)[idx]);
}

// XOR-swizzled 64x64 fp16 tile in LDS (attention): element (row,col) at
//   row*64 + ((col>>3) ^ (row&7))*8 + (col&7)
__device__ __forceinline__ const ushort* swz(const ushort* base, uint row, uint chunk){
  return base + (size_t)row*64u + (size_t)((chunk ^ (row & 7u))*8u);
}

// stage a 64x64 fp16 tile (row stride strideEl, 128B-contiguous rows) into
// swizzled LDS via global_load_lds width-16 (attention staging).
__device__ __forceinline__ void stage64(const ushort* g, uint strideEl,
                                        ushort* ldsbase, uint tid){
  uint w = tid >> 6;
  #pragma unroll
  for (int i = 0; i < 2; ++i){
    uint lc  = i*256u + tid;               // dest chunk id (16B units)
    uint row = lc >> 3, cp = lc & 7u;
    uint c   = cp ^ (row & 7u);            // swizzled source chunk
    const ushort* gp = g + (size_t)row*strideEl + c*8u;
    ushort* lp = ldsbase + (size_t)(i*256u + w*64u)*8u;   // wave-uniform base
    __builtin_amdgcn_global_load_lds((const __attribute__((address_space(1))) void*)gp,
        (__attribute__((address_space(3))) void*)lp, 16, 0, 0);
  }
}

// ---------------- input dtype detection --------------------------------------
__global__ __launch_bounds__(256) void kdetect(const uint* __restrict__ wi, int* __restrict__ flag){
  __shared__ int cnt;
  if (threadIdx.x == 0) cnt = 0;
  __syncthreads();
  uint w = wi[threadIdx.x];
  uint e = (w >> 7) & 0xFFu;
  if (e >= 100u && e <= 130u) atomicAdd(&cnt, 1);
  __syncthreads();
  if (threadIdx.x == 0) flag[0] = (cnt < 128) ? 1 : 0;
}

// ---------------- bias canonicalization -> fp32 (5120 elements) --------------
__global__ __launch_bounds__(256) void kbias(const void* bi, const void* bo,
                                             const void* bk, const void* bq, const void* bv,
                                             const int* __restrict__ flag,
                                             float* bi_f, float* bo_f, float* bqkv_f){
  int f = flag[0];
  uint id = blockIdx.x*256u + threadIdx.x;   // [0, 5120)
  if (id < 1024u)       bi_f[id]         = ldf(bi, id, f);
  else if (id < 2048u)  bo_f[id - 1024u] = ldf(bo, id - 1024u, f);
  else {
    uint j = id - 2048u;                     // [0,3072): sel*1024 + (h*64+e)
    uint sel = j >> 10, i = j & 1023u;
    const void* src = (sel == 0) ? bk : ((sel == 1) ? bq : bv);
    bqkv_f[j] = ldf(src, i, f);
  }
}

// ---------------- coalesced tiled transpose: out[c][r] = in[r][c], 1024x1024 --
__global__ __launch_bounds__(256) void ktranspose(const void* __restrict__ in,
                                                  const int* __restrict__ flag,
                                                  ushort* __restrict__ out){
  __shared__ float tile[64][65];
  int f = flag[0];
  uint R0 = blockIdx.x*64u, C0 = blockIdx.y*64u, t = threadIdx.x;
  #pragma unroll
  for (int i = 0; i < 16; ++i){
    uint id = i*256u + t, r = id >> 6, c = id & 63u;
    tile[r][c] = ldf(in, (size_t)(R0 + r)*1024u + C0 + c, f);
  }
  __syncthreads();
  #pragma unroll
  for (int i = 0; i < 16; ++i){
    uint id = i*256u + t, r = id >> 6, c = id & 63u;   // r = out-row (C-dim)
    out[(size_t)(C0 + r)*1024u + R0 + c] = f2h(tile[c][r]);
  }
}

// WqkvT[c][d] fp16, c = sel*1024 + h*64 + e ; W[sel] flat = h*65536 + d*64 + e
__global__ __launch_bounds__(256) void kqkvpack(const void* Wk, const void* Wq, const void* Wv,
                                                const int* __restrict__ flag,
                                                ushort* __restrict__ WqkvT){
  __shared__ float tile[64][65];
  int f = flag[0];
  uint sh = blockIdx.x;                 // sel*16 + h
  uint sel = sh >> 4, h = sh & 15u;
  uint D0 = blockIdx.y*64u, t = threadIdx.x;
  const void* W = (sel == 0) ? Wk : ((sel == 1) ? Wq : Wv);
  #pragma unroll
  for (int i = 0; i < 16; ++i){
    uint id = i*256u + t, r = id >> 6, c = id & 63u;   // r = d-local, c = e
    tile[r][c] = ldf(W, (size_t)h*65536u + (size_t)(D0 + r)*64u + c, f);
  }
  __syncthreads();
  #pragma unroll
  for (int i = 0; i < 16; ++i){
    uint id = i*256u + t, r = id >> 6, c = id & 63u;   // r = e, c = d-local
    WqkvT[(size_t)(sel*1024u + h*64u + r)*1024u + D0 + c] = f2h(tile[c][r]);
  }
}

// x -> canonical fp16 (16M elements, 8 per thread)
__global__ __launch_bounds__(256) void kcvt_x(const void* __restrict__ x,
                                              const int* __restrict__ flag,
                                              ushort* __restrict__ xh){
  int f = flag[0];
  size_t g = (size_t)(blockIdx.x*256u + threadIdx.x)*8u;
  ushort o[8];
  if (f){
    const float* xf = (const float*)x + g;
    #pragma unroll
    for (int i = 0; i < 8; ++i) o[i] = f2h(xf[i]);
  } else {
    const ushort* xb = (const ushort*)x + g;
    #pragma unroll
    for (int i = 0; i < 8; ++i) o[i] = f2h(bf2f(xb[i]));
  }
  *(uint4*)(xh + g) = *(uint4*)o;
}

// ============== GEMM: 256x256 tile, 8-phase pipelined schedule ===============
// C[M,N] = A[M,K] @ Bt[N,K]^T + bias.  BK=64 split into two k-halves of 32.
// LDS: sA/sB [buf][kh][256 rows][32 k] fp16, XOR-swizzled 16B chunks:
//   element (row,k) at row*32 + ((k>>3) ^ ((row>>1)&3))*8 + (k&7)
//   -> ds_read_b128 fragment reads hit 8 distinct 16B slots per 8 rows (free).
// Pipeline per K-tile t (4 phases; 16 MFMA each; stage 1 half-tile/phase):
//   ph1: read k0 m0-3 + all B(k0); stage A-k0' ; MFMA
//   ph2: read k0 m4-7;             stage B-k0' ; vmcnt(4) [retires buf[t].k1]
//   ph3: read k1 m0-3 + all B(k1); stage A-k1' ; MFMA
//   ph4: read k1 m4-7;             stage B-k1' ; vmcnt(4) [retires buf[t+1].k0]
// Counted vmcnt never drains to 0 in steady state (2 half-tiles in flight);
// raw s_barrier (no implicit waitcnt); setprio(1) around MFMA clusters.
// Hazards: every staged region's last reader finished >=2 barriers earlier.
template<int MODE>
__global__ __launch_bounds__(512, 2) void kgemm8(const ushort* __restrict__ A, const ushort* __restrict__ Bt,
                                                 const float* __restrict__ bias, void* __restrict__ Cv,
                                                 ushort* __restrict__ Vt, const int* __restrict__ dtf,
                                                 int M, int N, int K){
  __shared__ ushort sA[2][2][8192];   // 64 KB
  __shared__ ushort sB[2][2][8192];   // 64 KB
  uint tid = threadIdx.x, w = tid >> 6, lane = tid & 63u, quad = lane >> 4, l15 = lane & 15u;
  uint wm = w >> 2, wn = w & 3u;            // 2M x 4N waves
  uint bm = blockIdx.x, bn = blockIdx.y;
  uint cx = (quad ^ ((l15 >> 1) & 3u)) * 8u;  // swizzled chunk offset (ushort units)
  f32x4 acc[8][4] = {};

  const int NT = K >> 6;
  const ushort* GA0 = A  + (size_t)(bm*256u)*(size_t)K;
  const ushort* GB0 = Bt + (size_t)(bn*256u)*(size_t)K;

  // stage one [256][32] half-tile: 1024 chunks of 16B; 2 loads/thread.
  // dest chunk lc -> (row=lc>>2, cp=lc&3); source chunk c = cp ^ ((row>>1)&3).
  #define STAGE_HALF(G, DST)                                                        \
    {                                                                               \
      _Pragma("unroll")                                                             \
      for (int li = 0; li < 2; ++li){                                               \
        uint lc = (uint)li*512u + tid;                                              \
        uint row = lc >> 2, cp = lc & 3u;                                           \
        uint c = cp ^ ((row >> 1) & 3u);                                            \
        const ushort* gp = (G) + (size_t)row*(size_t)K + c*8u;                      \
        ushort* lp = (DST) + (size_t)((uint)li*512u + w*64u)*8u;                    \
        __builtin_amdgcn_global_load_lds((const __attribute__((address_space(1))) void*)gp, \
            (__attribute__((address_space(3))) void*)lp, 16, 0, 0);                 \
      }                                                                             \
    }

  // prologue: stage all 4 half-tiles of buf0; retire k0 halves, keep k1 in flight
  STAGE_HALF(GA0,       sA[0][0]);
  STAGE_HALF(GB0,       sB[0][0]);
  STAGE_HALF(GA0 + 32u, sA[0][1]);
  STAGE_HALF(GB0 + 32u, sB[0][1]);
  asm volatile("s_waitcnt vmcnt(4)" ::: "memory");
  __builtin_amdgcn_s_barrier();

  for (int t = 0; t < NT; ++t){
    uint bu = (uint)t & 1u, nbu = bu ^ 1u;
    const ushort* GA1 = GA0 + (size_t)(t + 1)*64u;
    const ushort* GB1 = GB0 + (size_t)(t + 1)*64u;
    bool more = (t + 1 < NT);

    f16x8 aF[4], bF[4];

    // ---- phase 1: k-half 0, m-frags 0-3, all n ----
    #pragma unroll
    for (int i = 0; i < 4; ++i) aF[i] = ld16(&sA[bu][0][(size_t)(wm*128u + (uint)i*16u + l15)*32u + cx]);
    #pragma unroll
    for (int j = 0; j < 4; ++j) bF[j] = ld16(&sB[bu][0][(size_t)(wn*64u + (uint)j*16u + l15)*32u + cx]);
    if (more) STAGE_HALF(GA1, sA[nbu][0]);
    __builtin_amdgcn_s_barrier();
    asm volatile("s_waitcnt lgkmcnt(0)" ::: "memory");
    __builtin_amdgcn_sched_barrier(0);
    __builtin_amdgcn_s_setprio(1);
    #pragma unroll
    for (int i = 0; i < 4; ++i)
      #pragma unroll
      for (int j = 0; j < 4; ++j)
        acc[i][j] = __builtin_amdgcn_mfma_f32_16x16x32_f16(aF[i], bF[j], acc[i][j], 0, 0, 0);
    __builtin_amdgcn_s_setprio(0);
    __builtin_amdgcn_s_barrier();

    // ---- phase 2: k-half 0, m-frags 4-7 (reuse bF) ----
    #pragma unroll
    for (int i = 0; i < 4; ++i) aF[i] = ld16(&sA[bu][0][(size_t)(wm*128u + (uint)(4+i)*16u + l15)*32u + cx]);
    if (more) STAGE_HALF(GB1, sB[nbu][0]);
    if (more) { asm volatile("s_waitcnt vmcnt(4)" ::: "memory"); }
    else      { asm volatile("s_waitcnt vmcnt(0)" ::: "memory"); }
    __builtin_amdgcn_s_barrier();
    asm volatile("s_waitcnt lgkmcnt(0)" ::: "memory");
    __builtin_amdgcn_sched_barrier(0);
    __builtin_amdgcn_s_setprio(1);
    #pragma unroll
    for (int i = 0; i < 4; ++i)
      #pragma unroll
      for (int j = 0; j < 4; ++j)
        acc[4+i][j] = __builtin_amdgcn_mfma_f32_16x16x32_f16(aF[i], bF[j], acc[4+i][j], 0, 0, 0);
    __builtin_amdgcn_s_setprio(0);
    __builtin_amdgcn_s_barrier();

    // ---- phase 3: k-half 1, m-frags 0-3, all n ----
    #pragma unroll
    for (int i = 0; i < 4; ++i) aF[i] = ld16(&sA[bu][1][(size_t)(wm*128u + (uint)i*16u + l15)*32u + cx]);
    #pragma unroll
    for (int j = 0; j < 4; ++j) bF[j] = ld16(&sB[bu][1][(size_t)(wn*64u + (uint)j*16u + l15)*32u + cx]);
    if (more) STAGE_HALF(GA1 + 32u, sA[nbu][1]);
    __builtin_amdgcn_s_barrier();
    asm volatile("s_waitcnt lgkmcnt(0)" ::: "memory");
    __builtin_amdgcn_sched_barrier(0);
    __builtin_amdgcn_s_setprio(1);
    #pragma unroll
    for (int i = 0; i < 4; ++i)
      #pragma unroll
      for (int j = 0; j < 4; ++j)
        acc[i][j] = __builtin_amdgcn_mfma_f32_16x16x32_f16(aF[i], bF[j], acc[i][j], 0, 0, 0);
    __builtin_amdgcn_s_setprio(0);
    __builtin_amdgcn_s_barrier();

    // ---- phase 4: k-half 1, m-frags 4-7 (reuse bF) ----
    #pragma unroll
    for (int i = 0; i < 4; ++i) aF[i] = ld16(&sA[bu][1][(size_t)(wm*128u + (uint)(4+i)*16u + l15)*32u + cx]);
    if (more) STAGE_HALF(GB1 + 32u, sB[nbu][1]);
    if (more) { asm volatile("s_waitcnt vmcnt(4)" ::: "memory"); }
    __builtin_amdgcn_s_barrier();
    asm volatile("s_waitcnt lgkmcnt(0)" ::: "memory");
    __builtin_amdgcn_sched_barrier(0);
    __builtin_amdgcn_s_setprio(1);
    #pragma unroll
    for (int i = 0; i < 4; ++i)
      #pragma unroll
      for (int j = 0; j < 4; ++j)
        acc[4+i][j] = __builtin_amdgcn_mfma_f32_16x16x32_f16(aF[i], bF[j], acc[4+i][j], 0, 0, 0);
    __builtin_amdgcn_s_setprio(0);
    __builtin_amdgcn_s_barrier();
  }
  #undef STAGE_HALF

  int f32out = (MODE == 2) ? dtf[0] : 0;
  #pragma unroll
  for (int j = 0; j < 4; ++j){
    uint col = bn*256u + wn*64u + (uint)j*16u + l15;
    float bj = bias[col];
    #pragma unroll
    for (int i = 0; i < 8; ++i){
      uint row0 = bm*256u + wm*128u + (uint)i*16u + quad*4u;
      #pragma unroll
      for (int r = 0; r < 4; ++r){
        float val = acc[i][j][r] + bj;
        uint row = row0 + (uint)r;
        if (MODE == 0){
          ((ushort*)Cv)[(size_t)row*N + col] = f2h(val);
        } else if (MODE == 1){
          if (col < 2048u){
            ((ushort*)Cv)[(size_t)row*2048u + col] = f2h(val);
          } else {
            uint c2 = col - 2048u;           // h*64+e ; row = b*512+s
            Vt[(size_t)(((row >> 9)*16u + (c2 >> 6))*64u + (c2 & 63u))*512u + (row & 511u)] = f2h(val);
          }
        } else {
          if (f32out) ((float*)Cv)[(size_t)row*N + col] = val;
          else        ((ushort*)Cv)[(size_t)row*N + col] = f2bf(val);
        }
      }
    }
  }
}

// ---------------- fused attention ("transposed" causal, flash-style) ---------
// S[t,s] = K[t,:]·Q[s,:], keep s<=t, softmax over s, O[t,:] = sum_s P[t,s]V[s,:]
// kq: fp16 [16384][2048]; Vt: fp16 [(b*16+h)*64+e][512]
// LPT: heavy (large tt) blocks launch first; light blocks backfill the tail.
__global__ __launch_bounds__(256, 4) void kattn(const ushort* __restrict__ kq,
                                                const ushort* __restrict__ Vt,
                                                ushort* __restrict__ Out){
  __shared__ ushort sQ[2][64*64];          // [s-local][d] swizzled   16 KB
  __shared__ ushort sV[2][64*64];          // [e][s-local] swizzled   16 KB
  __shared__ ushort pbuf[4][16*64];        // per-wave P (swizzled); K staging  8 KB
  uint tid = threadIdx.x, w = tid >> 6, lane = tid & 63u, quad = lane >> 4, l15 = lane & 15u;
  uint bh = blockIdx.x, tt = 7u - blockIdx.y;   // LPT: heavy tiles first
  uint b = bh >> 4, h = bh & 15u;
  uint t0 = tt*64u;
  const float L2E = 1.44269504088896340736f;
  const float MNEG = -1.0e30f;

  // stage K tile [t-local][d] into pbuf, Q0/V0 into buf 0 (all swizzled)
  stage64(kq + (size_t)(b*512u + t0)*2048u + h*64u, 2048u, (ushort*)pbuf, tid);
  stage64(kq + (size_t)(b*512u)*2048u + 1024u + h*64u, 2048u, sQ[0], tid);   // s0=0
  stage64(Vt + (size_t)(bh*64u)*512u, 512u, sV[0], tid);
  __syncthreads();

  f16x8 aK[2];  // K rows for this wave's 16 t's (wave-own pbuf rows)
  aK[0] = ld16(swz((const ushort*)pbuf, w*16u + l15, quad));
  aK[1] = ld16(swz((const ushort*)pbuf, w*16u + l15, 4u + quad));

  float m[4], l[4];
  f32x4 oacc[4];
  #pragma unroll
  for (int r = 0; r < 4; ++r){ m[r] = MNEG; l[r] = 0.f; }
  #pragma unroll
  for (int je = 0; je < 4; ++je) oacc[je] = (f32x4){0.f, 0.f, 0.f, 0.f};

  ushort* pw = (ushort*)pbuf + w*1024u;    // wave-private P region

  for (uint st = 0; st <= tt; ++st){
    uint cur = st & 1u;
    if (st) __syncthreads();               // staged bufs[cur] ready (vmcnt drained)
    if (st < tt){                          // prefetch st+1 with full-iter cover
      uint s1 = (st + 1u)*64u;
      stage64(kq + (size_t)(b*512u + s1)*2048u + 1024u + h*64u, 2048u, sQ[1u - cur], tid);
      stage64(Vt + (size_t)(bh*64u)*512u + s1, 512u, sV[1u - cur], tid);
    }
    f32x4 sacc[4];
    #pragma unroll
    for (int j = 0; j < 4; ++j){
      f16x8 bq0 = ld16(swz(sQ[cur], j*16u + l15, quad));
      f16x8 bq1 = ld16(swz(sQ[cur], j*16u + l15, 4u + quad));
      f32x4 s = (f32x4){0.f, 0.f, 0.f, 0.f};
      s = __builtin_amdgcn_mfma_f32_16x16x32_f16(aK[0], bq0, s, 0, 0, 0);
      s = __builtin_amdgcn_mfma_f32_16x16x32_f16(aK[1], bq1, s, 0, 0, 0);
      #pragma unroll
      for (int r = 0; r < 4; ++r) s[r] = fminf(fmaxf(s[r], MNEG), 1.0e30f);
      sacc[j] = s;
    }
    if (st == tt){  // diagonal tile: keep s<=t
      #pragma unroll
      for (int j = 0; j < 4; ++j)
        #pragma unroll
        for (int r = 0; r < 4; ++r)
          if (j*16u + l15 > w*16u + quad*4u + (uint)r) sacc[j][r] = MNEG;
    }
    float alpha[4];
    #pragma unroll
    for (int r = 0; r < 4; ++r){
      float v = fmaxf(fmaxf(sacc[0][r], sacc[1][r]), fmaxf(sacc[2][r], sacc[3][r]));
      v = fmaxf(v, __shfl_xor(v, 1));
      v = fmaxf(v, __shfl_xor(v, 2));
      v = fmaxf(v, __shfl_xor(v, 4));
      v = fmaxf(v, __shfl_xor(v, 8));
      float mn = fmaxf(m[r], v);
      alpha[r] = exp2f((m[r] - mn)*L2E);
      m[r] = mn;
    }
    #pragma unroll
    for (int j = 0; j < 4; ++j)
      #pragma unroll
      for (int r = 0; r < 4; ++r)
        sacc[j][r] = exp2f((sacc[j][r] - m[r])*L2E);
    #pragma unroll
    for (int r = 0; r < 4; ++r){
      float s = sacc[0][r] + sacc[1][r] + sacc[2][r] + sacc[3][r];
      s += __shfl_xor(s, 1);
      s += __shfl_xor(s, 2);
      s += __shfl_xor(s, 4);
      s += __shfl_xor(s, 8);
      l[r] = l[r]*alpha[r] + s;
    }
    #pragma unroll
    for (int je = 0; je < 4; ++je)
      #pragma unroll
      for (int r = 0; r < 4; ++r)
        oacc[je][r] *= alpha[r];
    // P: C/D layout -> wave-private swizzled LDS -> A-operand frags (no barrier)
    #pragma unroll
    for (int j = 0; j < 4; ++j)
      #pragma unroll
      for (int r = 0; r < 4; ++r){
        uint t = quad*4u + (uint)r;
        pw[t*64u + (((j*2u + (l15 >> 3)) ^ (t & 7u))*8u) + (l15 & 7u)] = f2h(sacc[j][r]);
      }
    f16x8 aP0 = ld16(swz(pw, l15, quad));
    f16x8 aP1 = ld16(swz(pw, l15, 4u + quad));
    #pragma unroll
    for (int je = 0; je < 4; ++je){
      f16x8 bv0 = ld16(swz(sV[cur], je*16u + l15, quad));
      f16x8 bv1 = ld16(swz(sV[cur], je*16u + l15, 4u + quad));
      oacc[je] = __builtin_amdgcn_mfma_f32_16x16x32_f16(aP0, bv0, oacc[je], 0, 0, 0);
      oacc[je] = __builtin_amdgcn_mfma_f32_16x16x32_f16(aP1, bv1, oacc[je], 0, 0, 0);
    }
  }
  float inv[4];
  #pragma unroll
  for (int r = 0; r < 4; ++r) inv[r] = 1.0f / l[r];
  #pragma unroll
  for (int je = 0; je < 4; ++je){
    uint e = h*64u + je*16u + l15;
    #pragma unroll
    for (int r = 0; r < 4; ++r){
      uint t = t0 + w*16u + quad*4u + (uint)r;
      Out[(size_t)(b*512u + t)*1024u + e] = f2h(oacc[je][r]*inv[r]);
    }
  }
}

// ---------------- launcher ---------------------------------------------------

extern "C" void kernel_launch(void* const* d_in, const int* in_sizes, int n_in,
                              void* d_out, int out_size, void* d_ws, size_t ws_size,
                              hipStream_t stream){
  const void* x  = d_in[0];
  const void* Wi = d_in[1];
  const void* bi = d_in[2];
  const void* Wk = d_in[3];
  const void* bk = d_in[4];
  const void* Wq = d_in[5];
  const void* bq = d_in[6];
  const void* Wv = d_in[7];
  const void* bv = d_in[8];
  const void* Wo = d_in[9];
  const void* bo = d_in[10];
  char* ws = (char*)d_ws;

  const size_t MB = 1u << 20;
  int*    flag   = (int*)ws;
  float*  bi_f   = (float*)(ws + 4096);                  // 4 KB
  float*  bo_f   = (float*)(ws + 8192);                  // 4 KB
  float*  bqkv_f = (float*)(ws + 12288);                 // 12 KB
  ushort* WiT    = (ushort*)(ws + 32768);                // 2 MB  (fp16)
  ushort* WoT    = (ushort*)(ws + 32768 + 2*MB);         // 2 MB
  ushort* WqkvT  = (ushort*)(ws + 32768 + 4*MB);         // 6 MB
  ushort* xh     = (ushort*)(ws + 32768 + 10*MB);        // 32 MB (dead after GEMM0)
  ushort* kq     = (ushort*)(ws + 32768 + 10*MB);        // 64 MB (overlays xh)
  ushort* hbuf   = (ushort*)(ws + 32768 + 74*MB);        // 32 MB (h, then attn out)
  ushort* Vt     = (ushort*)(ws + 32768 + 106*MB);       // 32 MB -> total ~138 MB

  kdetect<<<dim3(1), dim3(256), 0, stream>>>((const uint*)Wi, flag);
  kbias<<<dim3(20), dim3(256), 0, stream>>>(bi, bo, bk, bq, bv, flag, bi_f, bo_f, bqkv_f);
  ktranspose<<<dim3(16, 16), dim3(256), 0, stream>>>(Wi, flag, WiT);
  ktranspose<<<dim3(16, 16), dim3(256), 0, stream>>>(Wo, flag, WoT);
  kqkvpack<<<dim3(48, 16), dim3(256), 0, stream>>>(Wk, Wq, Wv, flag, WqkvT);
  kcvt_x<<<dim3(8192), dim3(256), 0, stream>>>(x, flag, xh);

  kgemm8<0><<<dim3(64, 4),  dim3(512), 0, stream>>>(xh,   WiT,   bi_f,   hbuf, nullptr, nullptr, NTOK, 1024, 1024);
  kgemm8<1><<<dim3(64, 12), dim3(512), 0, stream>>>(hbuf, WqkvT, bqkv_f, kq,   Vt,      nullptr, NTOK, 3072, 1024);
  kattn<<<dim3(512, 8), dim3(256), 0, stream>>>(kq, Vt, hbuf);
  kgemm8<2><<<dim3(64, 4),  dim3(512), 0, stream>>>(hbuf, WoT,   bo_f,   d_out, nullptr, flag,   NTOK, 1024, 1024);
}

// Round 3
// 502.805 us; speedup vs baseline: 1.0260x; 1.0260x over previous
//
#include <hip/hip_runtime.h>
#include <hip/hip_bf16.h>
#include <stdint.h>

// B=32, T=512, D=1024, H=16, HD=64
#define NTOK 16384

typedef _Float16 f16;
typedef f16   f16x8 __attribute__((ext_vector_type(8)));
typedef float f32x4 __attribute__((ext_vector_type(4)));

__device__ __forceinline__ float bf2f(ushort h){
  union { uint32_t u; float f; } v; v.u = ((uint32_t)h) << 16; return v.f;
}
__device__ __forceinline__ ushort f2bf(float f){
  union { float f; uint32_t u; } v; v.f = f;
  uint32_t u = v.u;
  return (ushort)((u + 0x7FFFu + ((u >> 16) & 1u)) >> 16);  // RNE
}
__device__ __forceinline__ ushort f2h(float f){          // fp32 -> fp16 bits (RNE)
  return __builtin_bit_cast(ushort, (f16)f);
}
__device__ __forceinline__ f16x8 ld16(const ushort* p){  // 8 fp16
  uint4 u = *(const uint4*)p;
  return __builtin_bit_cast(f16x8, u);
}
// dtype-flexible fp32 load: fp32 path direct, bf16 path converts
__device__ __forceinline__ float ldf(const void* p, size_t idx, int isf32){
  if (isf32) return ((const float*)p)[idx];
  return bf2f(((const ushort*)p)[idx]);
}

// XOR-swizzled 64x64 fp16 tile in LDS: element (row,col) lives at
//   row*64 + ((col>>3) ^ (row&7))*8 + (col&7)
__device__ __forceinline__ const ushort* swz(const ushort* base, uint row, uint chunk){
  return base + (size_t)row*64u + (size_t)((chunk ^ (row & 7u))*8u);
}

// stage a 64x64 fp16 tile (row stride strideEl, 128B-contiguous rows) into
// swizzled LDS via global_load_lds width-16. Dest chunk is forced to be
// wave-uniform-base + lane*16B; we permute the SOURCE chunk instead (free).
__device__ __forceinline__ void stage64(const ushort* g, uint strideEl,
                                        ushort* ldsbase, uint tid){
  uint w = tid >> 6;
  #pragma unroll
  for (int i = 0; i < 2; ++i){
    uint lc  = i*256u + tid;               // dest chunk id (16B units)
    uint row = lc >> 3, cp = lc & 7u;
    uint c   = cp ^ (row & 7u);            // swizzled source chunk
    const ushort* gp = g + (size_t)row*strideEl + c*8u;
    ushort* lp = ldsbase + (size_t)(i*256u + w*64u)*8u;   // wave-uniform base
    __builtin_amdgcn_global_load_lds((const __attribute__((address_space(1))) void*)gp,
        (__attribute__((address_space(3))) void*)lp, 16, 0, 0);
  }
}

// ---------------- input dtype detection --------------------------------------
__global__ __launch_bounds__(256) void kdetect(const uint* __restrict__ wi, int* __restrict__ flag){
  __shared__ int cnt;
  if (threadIdx.x == 0) cnt = 0;
  __syncthreads();
  uint w = wi[threadIdx.x];
  uint e = (w >> 7) & 0xFFu;
  if (e >= 100u && e <= 130u) atomicAdd(&cnt, 1);
  __syncthreads();
  if (threadIdx.x == 0) flag[0] = (cnt < 128) ? 1 : 0;
}

// ---------------- bias canonicalization -> fp32 (5120 elements) --------------
__global__ __launch_bounds__(256) void kbias(const void* bi, const void* bo,
                                             const void* bk, const void* bq, const void* bv,
                                             const int* __restrict__ flag,
                                             float* bi_f, float* bo_f, float* bqkv_f){
  int f = flag[0];
  uint id = blockIdx.x*256u + threadIdx.x;   // [0, 5120)
  if (id < 1024u)       bi_f[id]         = ldf(bi, id, f);
  else if (id < 2048u)  bo_f[id - 1024u] = ldf(bo, id - 1024u, f);
  else {
    uint j = id - 2048u;                     // [0,3072): sel*1024 + (h*64+e)
    uint sel = j >> 10, i = j & 1023u;
    const void* src = (sel == 0) ? bk : ((sel == 1) ? bq : bv);
    bqkv_f[j] = ldf(src, i, f);
  }
}

// ---------------- coalesced tiled transpose: out[c][r] = in[r][c], 1024x1024 --
__global__ __launch_bounds__(256) void ktranspose(const void* __restrict__ in,
                                                  const int* __restrict__ flag,
                                                  ushort* __restrict__ out){
  __shared__ float tile[64][65];
  int f = flag[0];
  uint R0 = blockIdx.x*64u, C0 = blockIdx.y*64u, t = threadIdx.x;
  #pragma unroll
  for (int i = 0; i < 16; ++i){
    uint id = i*256u + t, r = id >> 6, c = id & 63u;
    tile[r][c] = ldf(in, (size_t)(R0 + r)*1024u + C0 + c, f);
  }
  __syncthreads();
  #pragma unroll
  for (int i = 0; i < 16; ++i){
    uint id = i*256u + t, r = id >> 6, c = id & 63u;   // r = out-row (C-dim)
    out[(size_t)(C0 + r)*1024u + R0 + c] = f2h(tile[c][r]);
  }
}

// WqkvT[c][d] fp16, c = sel*1024 + h*64 + e ; W[sel] flat = h*65536 + d*64 + e
__global__ __launch_bounds__(256) void kqkvpack(const void* Wk, const void* Wq, const void* Wv,
                                                const int* __restrict__ flag,
                                                ushort* __restrict__ WqkvT){
  __shared__ float tile[64][65];
  int f = flag[0];
  uint sh = blockIdx.x;                 // sel*16 + h
  uint sel = sh >> 4, h = sh & 15u;
  uint D0 = blockIdx.y*64u, t = threadIdx.x;
  const void* W = (sel == 0) ? Wk : ((sel == 1) ? Wq : Wv);
  #pragma unroll
  for (int i = 0; i < 16; ++i){
    uint id = i*256u + t, r = id >> 6, c = id & 63u;   // r = d-local, c = e
    tile[r][c] = ldf(W, (size_t)h*65536u + (size_t)(D0 + r)*64u + c, f);
  }
  __syncthreads();
  #pragma unroll
  for (int i = 0; i < 16; ++i){
    uint id = i*256u + t, r = id >> 6, c = id & 63u;   // r = e, c = d-local
    WqkvT[(size_t)(sel*1024u + h*64u + r)*1024u + D0 + c] = f2h(tile[c][r]);
  }
}

// x -> canonical fp16 (16M elements, 8 per thread) — vectorized loads
__global__ __launch_bounds__(256) void kcvt_x(const void* __restrict__ x,
                                              const int* __restrict__ flag,
                                              ushort* __restrict__ xh){
  int f = flag[0];
  size_t g = (size_t)(blockIdx.x*256u + threadIdx.x)*8u;
  ushort o[8];
  if (f){
    const float4* xf = (const float4*)((const float*)x + g);
    float4 a = xf[0], b = xf[1];
    o[0] = f2h(a.x); o[1] = f2h(a.y); o[2] = f2h(a.z); o[3] = f2h(a.w);
    o[4] = f2h(b.x); o[5] = f2h(b.y); o[6] = f2h(b.z); o[7] = f2h(b.w);
  } else {
    uint4 u = *(const uint4*)((const ushort*)x + g);
    ushort s[8];
    *(uint4*)s = u;
    #pragma unroll
    for (int i = 0; i < 8; ++i) o[i] = f2h(bf2f(s[i]));
  }
  *(uint4*)(xh + g) = *(uint4*)o;
}

// ---------------- GEMM: C[M,N] = A[M,K] @ Bt[N,K]^T + bias (fp16, m97) -------
// launch_bounds(256,4): VGPR 56 + AGPR 64 = 120 <= 128 -> 4 blocks/CU; the
// N=1024 GEMMs (1024 blocks) then run in exactly ONE dispatch round.
// MODE 1: q-columns (1024..2047) are pre-scaled by log2(e) in f32 before the
// single f2h rounding — folds the softmax base-2 conversion into the GEMM at
// zero extra quantization cost; kattn then uses exp2 directly.
template<int MODE>
__global__ __launch_bounds__(256, 4) void kgemm(const ushort* __restrict__ A, const ushort* __restrict__ Bt,
                                                const float* __restrict__ bias, void* __restrict__ Cv,
                                                ushort* __restrict__ Vt, const int* __restrict__ dtf,
                                                int M, int N, int K){
  __shared__ ushort sA[128*32];
  __shared__ ushort sB[128*32];
  uint tid = threadIdx.x, w = tid >> 6, lane = tid & 63u, quad = lane >> 4, l15 = lane & 15u;
  uint bm = blockIdx.x, bn = blockIdx.y;
  uint wm = w >> 1, wn = w & 1u;
  f32x4 acc[4][4] = {};

  for (int k0 = 0; k0 < K; k0 += 32){
    #pragma unroll
    for (int i = 0; i < 2; ++i){
      uint c   = (w*2u + i)*64u + lane;     // 16B chunk id within tile
      uint row = c >> 2, ko = (c & 3u)*8u;  // [128][32] row-major, 4 chunks/row
      const ushort* gA = A  + (size_t)(bm*128u + row)*K + k0 + ko;
      const ushort* gB = Bt + (size_t)(bn*128u + row)*K + k0 + ko;
      __builtin_amdgcn_global_load_lds((const __attribute__((address_space(1))) void*)gA,
          (__attribute__((address_space(3))) void*)(sA + (w*2u + i)*512u), 16, 0, 0);
      __builtin_amdgcn_global_load_lds((const __attribute__((address_space(1))) void*)gB,
          (__attribute__((address_space(3))) void*)(sB + (w*2u + i)*512u), 16, 0, 0);
    }
    __syncthreads();
    f16x8 aF[4], bF[4];
    #pragma unroll
    for (int i = 0; i < 4; ++i) aF[i] = *(const f16x8*)(sA + (wm*64u + i*16u + l15)*32u + quad*8u);
    #pragma unroll
    for (int j = 0; j < 4; ++j) bF[j] = *(const f16x8*)(sB + (wn*64u + j*16u + l15)*32u + quad*8u);
    #pragma unroll
    for (int i = 0; i < 4; ++i)
      #pragma unroll
      for (int j = 0; j < 4; ++j)
        acc[i][j] = __builtin_amdgcn_mfma_f32_16x16x32_f16(aF[i], bF[j], acc[i][j], 0, 0, 0);
    __syncthreads();
  }
  int f32out = (MODE == 2) ? dtf[0] : 0;
  const float L2E = 1.44269504088896340736f;
  #pragma unroll
  for (int j = 0; j < 4; ++j){
    uint col = bn*128u + wn*64u + j*16u + l15;
    float bj = bias[col];
    #pragma unroll
    for (int i = 0; i < 4; ++i){
      uint row0 = bm*128u + wm*64u + i*16u + quad*4u;
      #pragma unroll
      for (int r = 0; r < 4; ++r){
        float val = acc[i][j][r] + bj;
        uint row = row0 + r;
        if (MODE == 0){
          ((ushort*)Cv)[(size_t)row*N + col] = f2h(val);
        } else if (MODE == 1){
          if (col < 2048u){
            float v2 = (col >= 1024u) ? val * L2E : val;   // q pre-scaled by log2(e)
            ((ushort*)Cv)[(size_t)row*2048u + col] = f2h(v2);
          } else {
            uint c2 = col - 2048u;           // h*64+e ; row = b*512+s
            Vt[(size_t)(((row >> 9)*16u + (c2 >> 6))*64u + (c2 & 63u))*512u + (row & 511u)] = f2h(val);
          }
        } else {
          if (f32out) ((float*)Cv)[(size_t)row*N + col] = val;
          else        ((ushort*)Cv)[(size_t)row*N + col] = f2bf(val);
        }
      }
    }
  }
}

// ---------------- fused attention ("transposed" causal, flash-style) ---------
// S[t,s] = K[t,:]·Q[s,:], keep s<=t, softmax over s, O[t,:] = sum_s P[t,s]V[s,:]
// kq: fp16 [16384][2048] (q pre-scaled by log2e); Vt: fp16 [(b*16+h)*64+e][512]
// S is already in log2 domain -> exp2 directly, no per-element scale, no clamp
// (S is an f32 MFMA accum of O(10) fp16 values; cannot overflow/NaN).
// LPT: heavy (large tt) blocks launch first; light blocks backfill the tail.
__global__ __launch_bounds__(256, 4) void kattn(const ushort* __restrict__ kq,
                                                const ushort* __restrict__ Vt,
                                                ushort* __restrict__ Out){
  __shared__ ushort sQ[2][64*64];          // [s-local][d] swizzled   16 KB
  __shared__ ushort sV[2][64*64];          // [e][s-local] swizzled   16 KB
  __shared__ ushort pbuf[4][16*64];        // per-wave P (swizzled); K staging  8 KB
  uint tid = threadIdx.x, w = tid >> 6, lane = tid & 63u, quad = lane >> 4, l15 = lane & 15u;
  uint bh = blockIdx.x, tt = 7u - blockIdx.y;   // LPT: heavy tiles first
  uint b = bh >> 4, h = bh & 15u;
  uint t0 = tt*64u;
  const float MNEG = -1.0e30f;

  // stage K tile [t-local][d] into pbuf, Q0/V0 into buf 0 (all swizzled)
  stage64(kq + (size_t)(b*512u + t0)*2048u + h*64u, 2048u, (ushort*)pbuf, tid);
  stage64(kq + (size_t)(b*512u)*2048u + 1024u + h*64u, 2048u, sQ[0], tid);   // s0=0
  stage64(Vt + (size_t)(bh*64u)*512u, 512u, sV[0], tid);
  __syncthreads();

  f16x8 aK[2];  // K rows for this wave's 16 t's (wave-own pbuf rows)
  aK[0] = ld16(swz((const ushort*)pbuf, w*16u + l15, quad));
  aK[1] = ld16(swz((const ushort*)pbuf, w*16u + l15, 4u + quad));

  float m[4], l[4];
  f32x4 oacc[4];
  #pragma unroll
  for (int r = 0; r < 4; ++r){ m[r] = MNEG; l[r] = 0.f; }
  #pragma unroll
  for (int je = 0; je < 4; ++je) oacc[je] = (f32x4){0.f, 0.f, 0.f, 0.f};

  ushort* pw = (ushort*)pbuf + w*1024u;    // wave-private P region

  for (uint st = 0; st <= tt; ++st){
    uint cur = st & 1u;
    if (st) __syncthreads();               // staged bufs[cur] ready (vmcnt drained)
    if (st < tt){                          // prefetch st+1 with full-iter cover
      uint s1 = (st + 1u)*64u;
      stage64(kq + (size_t)(b*512u + s1)*2048u + 1024u + h*64u, 2048u, sQ[1u - cur], tid);
      stage64(Vt + (size_t)(bh*64u)*512u + s1, 512u, sV[1u - cur], tid);
    }
    f32x4 sacc[4];
    #pragma unroll
    for (int j = 0; j < 4; ++j){
      f16x8 bq0 = ld16(swz(sQ[cur], j*16u + l15, quad));
      f16x8 bq1 = ld16(swz(sQ[cur], j*16u + l15, 4u + quad));
      f32x4 s = (f32x4){0.f, 0.f, 0.f, 0.f};
      s = __builtin_amdgcn_mfma_f32_16x16x32_f16(aK[0], bq0, s, 0, 0, 0);
      s = __builtin_amdgcn_mfma_f32_16x16x32_f16(aK[1], bq1, s, 0, 0, 0);
      sacc[j] = s;
    }
    if (st == tt){  // diagonal tile: keep s<=t
      #pragma unroll
      for (int j = 0; j < 4; ++j)
        #pragma unroll
        for (int r = 0; r < 4; ++r)
          if (j*16u + l15 > w*16u + quad*4u + (uint)r) sacc[j][r] = MNEG;
    }
    float alpha[4];
    #pragma unroll
    for (int r = 0; r < 4; ++r){
      float v = fmaxf(fmaxf(sacc[0][r], sacc[1][r]), fmaxf(sacc[2][r], sacc[3][r]));
      v = fmaxf(v, __shfl_xor(v, 1));
      v = fmaxf(v, __shfl_xor(v, 2));
      v = fmaxf(v, __shfl_xor(v, 4));
      v = fmaxf(v, __shfl_xor(v, 8));
      float mn = fmaxf(m[r], v);
      alpha[r] = exp2f(m[r] - mn);         // already log2-domain
      m[r] = mn;
    }
    #pragma unroll
    for (int j = 0; j < 4; ++j)
      #pragma unroll
      for (int r = 0; r < 4; ++r)
        sacc[j][r] = exp2f(sacc[j][r] - m[r]);
    #pragma unroll
    for (int r = 0; r < 4; ++r){
      float s = sacc[0][r] + sacc[1][r] + sacc[2][r] + sacc[3][r];
      s += __shfl_xor(s, 1);
      s += __shfl_xor(s, 2);
      s += __shfl_xor(s, 4);
      s += __shfl_xor(s, 8);
      l[r] = l[r]*alpha[r] + s;
    }
    #pragma unroll
    for (int je = 0; je < 4; ++je)
      #pragma unroll
      for (int r = 0; r < 4; ++r)
        oacc[je][r] *= alpha[r];
    // P: C/D layout -> wave-private swizzled LDS -> A-operand frags (no barrier)
    #pragma unroll
    for (int j = 0; j < 4; ++j)
      #pragma unroll
      for (int r = 0; r < 4; ++r){
        uint t = quad*4u + (uint)r;
        pw[t*64u + (((j*2u + (l15 >> 3)) ^ (t & 7u))*8u) + (l15 & 7u)] = f2h(sacc[j][r]);
      }
    f16x8 aP0 = ld16(swz(pw, l15, quad));
    f16x8 aP1 = ld16(swz(pw, l15, 4u + quad));
    #pragma unroll
    for (int je = 0; je < 4; ++je){
      f16x8 bv0 = ld16(swz(sV[cur], je*16u + l15, quad));
      f16x8 bv1 = ld16(swz(sV[cur], je*16u + l15, 4u + quad));
      oacc[je] = __builtin_amdgcn_mfma_f32_16x16x32_f16(aP0, bv0, oacc[je], 0, 0, 0);
      oacc[je] = __builtin_amdgcn_mfma_f32_16x16x32_f16(aP1, bv1, oacc[je], 0, 0, 0);
    }
  }
  float inv[4];
  #pragma unroll
  for (int r = 0; r < 4; ++r) inv[r] = 1.0f / l[r];
  #pragma unroll
  for (int je = 0; je < 4; ++je){
    uint e = h*64u + je*16u + l15;
    #pragma unroll
    for (int r = 0; r < 4; ++r){
      uint t = t0 + w*16u + quad*4u + (uint)r;
      Out[(size_t)(b*512u + t)*1024u + e] = f2h(oacc[je][r]*inv[r]);
    }
  }
}

// ---------------- launcher ---------------------------------------------------

extern "C" void kernel_launch(void* const* d_in, const int* in_sizes, int n_in,
                              void* d_out, int out_size, void* d_ws, size_t ws_size,
                              hipStream_t stream){
  const void* x  = d_in[0];
  const void* Wi = d_in[1];
  const void* bi = d_in[2];
  const void* Wk = d_in[3];
  const void* bk = d_in[4];
  const void* Wq = d_in[5];
  const void* bq = d_in[6];
  const void* Wv = d_in[7];
  const void* bv = d_in[8];
  const void* Wo = d_in[9];
  const void* bo = d_in[10];
  char* ws = (char*)d_ws;

  const size_t MB = 1u << 20;
  int*    flag   = (int*)ws;
  float*  bi_f   = (float*)(ws + 4096);                  // 4 KB
  float*  bo_f   = (float*)(ws + 8192);                  // 4 KB
  float*  bqkv_f = (float*)(ws + 12288);                 // 12 KB
  ushort* WiT    = (ushort*)(ws + 32768);                // 2 MB  (fp16)
  ushort* WoT    = (ushort*)(ws + 32768 + 2*MB);         // 2 MB
  ushort* WqkvT  = (ushort*)(ws + 32768 + 4*MB);         // 6 MB
  ushort* xh     = (ushort*)(ws + 32768 + 10*MB);        // 32 MB (dead after GEMM0)
  ushort* kq     = (ushort*)(ws + 32768 + 10*MB);        // 64 MB (overlays xh)
  ushort* hbuf   = (ushort*)(ws + 32768 + 74*MB);        // 32 MB (h, then attn out)
  ushort* Vt     = (ushort*)(ws + 32768 + 106*MB);       // 32 MB -> total ~138 MB

  kdetect<<<dim3(1), dim3(256), 0, stream>>>((const uint*)Wi, flag);
  kbias<<<dim3(20), dim3(256), 0, stream>>>(bi, bo, bk, bq, bv, flag, bi_f, bo_f, bqkv_f);
  ktranspose<<<dim3(16, 16), dim3(256), 0, stream>>>(Wi, flag, WiT);
  ktranspose<<<dim3(16, 16), dim3(256), 0, stream>>>(Wo, flag, WoT);
  kqkvpack<<<dim3(48, 16), dim3(256), 0, stream>>>(Wk, Wq, Wv, flag, WqkvT);
  kcvt_x<<<dim3(8192), dim3(256), 0, stream>>>(x, flag, xh);

  kgemm<0><<<dim3(128, 8),  dim3(256), 0, stream>>>(xh,   WiT,   bi_f,   hbuf, nullptr, nullptr, NTOK, 1024, 1024);
  kgemm<1><<<dim3(128, 24), dim3(256), 0, stream>>>(hbuf, WqkvT, bqkv_f, kq,   Vt,      nullptr, NTOK, 3072, 1024);
  kattn<<<dim3(512, 8), dim3(256), 0, stream>>>(kq, Vt, hbuf);
  kgemm<2><<<dim3(128, 8),  dim3(256), 0, stream>>>(hbuf, WoT,   bo_f,   d_out, nullptr, flag,   NTOK, 1024, 1024);
}

// Round 4
// 452.039 us; speedup vs baseline: 1.1413x; 1.1123x over previous
//
#include <hip/hip_runtime.h>
#include <hip/hip_bf16.h>
#include <stdint.h>

// B=32, T=512, D=1024, H=16, HD=64
#define NTOK 16384

typedef _Float16 f16;
typedef f16   f16x8 __attribute__((ext_vector_type(8)));
typedef float f32x4 __attribute__((ext_vector_type(4)));

__device__ __forceinline__ float bf2f(ushort h){
  union { uint32_t u; float f; } v; v.u = ((uint32_t)h) << 16; return v.f;
}
__device__ __forceinline__ ushort f2bf(float f){
  union { float f; uint32_t u; } v; v.f = f;
  uint32_t u = v.u;
  return (ushort)((u + 0x7FFFu + ((u >> 16) & 1u)) >> 16);  // RNE
}
__device__ __forceinline__ ushort f2h(float f){          // fp32 -> fp16 bits (RNE)
  return __builtin_bit_cast(ushort, (f16)f);
}
__device__ __forceinline__ f16x8 ld16(const ushort* p){  // 8 fp16
  uint4 u = *(const uint4*)p;
  return __builtin_bit_cast(f16x8, u);
}
// dtype-flexible fp32 load: fp32 path direct, bf16 path converts
__device__ __forceinline__ float ldf(const void* p, size_t idx, int isf32){
  if (isf32) return ((const float*)p)[idx];
  return bf2f(((const ushort*)p)[idx]);
}

// XOR-swizzled [*][64] fp16 tile in LDS: element (row,col) lives at
//   row*64 + ((col>>3) ^ (row&7))*8 + (col&7)
// -> b128 fragment reads hit 8 distinct bank groups instead of serializing.
__device__ __forceinline__ const ushort* swz(const ushort* base, uint row, uint chunk){
  return base + (size_t)row*64u + (size_t)((chunk ^ (row & 7u))*8u);
}

// stage a 64x64 fp16 tile (row stride strideEl, 128B-contiguous rows) into
// swizzled LDS via global_load_lds width-16. Dest chunk is forced to be
// wave-uniform-base + lane*16B; we permute the SOURCE chunk instead (free).
__device__ __forceinline__ void stage64(const ushort* g, uint strideEl,
                                        ushort* ldsbase, uint tid){
  uint w = tid >> 6;
  #pragma unroll
  for (int i = 0; i < 2; ++i){
    uint lc  = i*256u + tid;               // dest chunk id (16B units)
    uint row = lc >> 3, cp = lc & 7u;
    uint c   = cp ^ (row & 7u);            // swizzled source chunk
    const ushort* gp = g + (size_t)row*strideEl + c*8u;
    ushort* lp = ldsbase + (size_t)(i*256u + w*64u)*8u;   // wave-uniform base
    __builtin_amdgcn_global_load_lds((const __attribute__((address_space(1))) void*)gp,
        (__attribute__((address_space(3))) void*)lp, 16, 0, 0);
  }
}

// stage a 128x64 fp16 tile (row stride K) into swizzled LDS (GEMM staging).
__device__ __forceinline__ void stage128(const ushort* g, int K,
                                         ushort* ldsbase, uint tid){
  uint w = tid >> 6;
  #pragma unroll
  for (int i = 0; i < 4; ++i){
    uint lc  = i*256u + tid;               // dest chunk id in [0,1024)
    uint row = lc >> 3, cp = lc & 7u;
    uint c   = cp ^ (row & 7u);            // swizzled source chunk
    const ushort* gp = g + (size_t)row*(size_t)K + c*8u;
    ushort* lp = ldsbase + (size_t)(i*256u + w*64u)*8u;   // wave-uniform base
    __builtin_amdgcn_global_load_lds((const __attribute__((address_space(1))) void*)gp,
        (__attribute__((address_space(3))) void*)lp, 16, 0, 0);
  }
}

// ---------------- input dtype detection --------------------------------------
__global__ __launch_bounds__(256) void kdetect(const uint* __restrict__ wi, int* __restrict__ flag){
  __shared__ int cnt;
  if (threadIdx.x == 0) cnt = 0;
  __syncthreads();
  uint w = wi[threadIdx.x];
  uint e = (w >> 7) & 0xFFu;
  if (e >= 100u && e <= 130u) atomicAdd(&cnt, 1);
  __syncthreads();
  if (threadIdx.x == 0) flag[0] = (cnt < 128) ? 1 : 0;
}

// ---------------- bias canonicalization -> fp32 (5120 elements) --------------
__global__ __launch_bounds__(256) void kbias(const void* bi, const void* bo,
                                             const void* bk, const void* bq, const void* bv,
                                             const int* __restrict__ flag,
                                             float* bi_f, float* bo_f, float* bqkv_f){
  int f = flag[0];
  uint id = blockIdx.x*256u + threadIdx.x;   // [0, 5120)
  if (id < 1024u)       bi_f[id]         = ldf(bi, id, f);
  else if (id < 2048u)  bo_f[id - 1024u] = ldf(bo, id - 1024u, f);
  else {
    uint j = id - 2048u;                     // [0,3072): sel*1024 + (h*64+e)
    uint sel = j >> 10, i = j & 1023u;
    const void* src = (sel == 0) ? bk : ((sel == 1) ? bq : bv);
    bqkv_f[j] = ldf(src, i, f);
  }
}

// ---------------- coalesced tiled transpose: out[c][r] = in[r][c], 1024x1024 --
__global__ __launch_bounds__(256) void ktranspose(const void* __restrict__ in,
                                                  const int* __restrict__ flag,
                                                  ushort* __restrict__ out){
  __shared__ float tile[64][65];
  int f = flag[0];
  uint R0 = blockIdx.x*64u, C0 = blockIdx.y*64u, t = threadIdx.x;
  #pragma unroll
  for (int i = 0; i < 16; ++i){
    uint id = i*256u + t, r = id >> 6, c = id & 63u;
    tile[r][c] = ldf(in, (size_t)(R0 + r)*1024u + C0 + c, f);
  }
  __syncthreads();
  #pragma unroll
  for (int i = 0; i < 16; ++i){
    uint id = i*256u + t, r = id >> 6, c = id & 63u;   // r = out-row (C-dim)
    out[(size_t)(C0 + r)*1024u + R0 + c] = f2h(tile[c][r]);
  }
}

// WqkvT[c][d] fp16, c = sel*1024 + h*64 + e ; W[sel] flat = h*65536 + d*64 + e
__global__ __launch_bounds__(256) void kqkvpack(const void* Wk, const void* Wq, const void* Wv,
                                                const int* __restrict__ flag,
                                                ushort* __restrict__ WqkvT){
  __shared__ float tile[64][65];
  int f = flag[0];
  uint sh = blockIdx.x;                 // sel*16 + h
  uint sel = sh >> 4, h = sh & 15u;
  uint D0 = blockIdx.y*64u, t = threadIdx.x;
  const void* W = (sel == 0) ? Wk : ((sel == 1) ? Wq : Wv);
  #pragma unroll
  for (int i = 0; i < 16; ++i){
    uint id = i*256u + t, r = id >> 6, c = id & 63u;   // r = d-local, c = e
    tile[r][c] = ldf(W, (size_t)h*65536u + (size_t)(D0 + r)*64u + c, f);
  }
  __syncthreads();
  #pragma unroll
  for (int i = 0; i < 16; ++i){
    uint id = i*256u + t, r = id >> 6, c = id & 63u;   // r = e, c = d-local
    WqkvT[(size_t)(sel*1024u + h*64u + r)*1024u + D0 + c] = f2h(tile[c][r]);
  }
}

// x -> canonical fp16 (16M elements, 8 per thread) — vectorized loads
__global__ __launch_bounds__(256) void kcvt_x(const void* __restrict__ x,
                                              const int* __restrict__ flag,
                                              ushort* __restrict__ xh){
  int f = flag[0];
  size_t g = (size_t)(blockIdx.x*256u + threadIdx.x)*8u;
  ushort o[8];
  if (f){
    const float4* xf = (const float4*)((const float*)x + g);
    float4 a = xf[0], b = xf[1];
    o[0] = f2h(a.x); o[1] = f2h(a.y); o[2] = f2h(a.z); o[3] = f2h(a.w);
    o[4] = f2h(b.x); o[5] = f2h(b.y); o[6] = f2h(b.z); o[7] = f2h(b.w);
  } else {
    uint4 u = *(const uint4*)((const ushort*)x + g);
    ushort s[8];
    *(uint4*)s = u;
    #pragma unroll
    for (int i = 0; i < 8; ++i) o[i] = f2h(bf2f(s[i]));
  }
  *(uint4*)(xh + g) = *(uint4*)o;
}

// ---------------- GEMM: C[M,N] = A[M,K] @ Bt[N,K]^T + bias (fp16) ------------
// m97 structure, BK=64 (half the barriers of BK=32; 32 MFMA per barrier-pair),
// XOR-swizzled [128][64] LDS tiles (same involution as kattn: source chunk
// pre-swizzle + swizzled read) -> conflict-free b128 fragment reads.
// LDS 32 KB -> still 4 blocks/CU with launch_bounds(256,4).
// MODE 0: fp16 out [M,N].   MODE 2: final out, dtf picks f32/bf16.
// MODE 3: kq out [M,2048], q-cols (>=1024) pre-scaled by log2(e) in f32 before
//         the single f2h rounding (folds softmax base-2 conversion, free).
// MODE 4: V out, col = h*64+e local in [0,1024) -> Vt scatter [(b,h,e)][s].
template<int MODE>
__global__ __launch_bounds__(256, 4) void kgemm(const ushort* __restrict__ A, const ushort* __restrict__ Bt,
                                                const float* __restrict__ bias, void* __restrict__ Cv,
                                                ushort* __restrict__ Vt, const int* __restrict__ dtf,
                                                int M, int N, int K){
  __shared__ ushort sA[128*64];   // 16 KB, swizzled
  __shared__ ushort sB[128*64];   // 16 KB, swizzled
  uint tid = threadIdx.x, w = tid >> 6, lane = tid & 63u, quad = lane >> 4, l15 = lane & 15u;
  uint bm = blockIdx.x, bn = blockIdx.y;
  uint wm = w >> 1, wn = w & 1u;
  f32x4 acc[4][4] = {};

  for (int k0 = 0; k0 < K; k0 += 64){
    stage128(A  + (size_t)(bm*128u)*(size_t)K + k0, K, sA, tid);
    stage128(Bt + (size_t)(bn*128u)*(size_t)K + k0, K, sB, tid);
    __syncthreads();
    #pragma unroll
    for (int kk = 0; kk < 2; ++kk){
      f16x8 aF[4], bF[4];
      #pragma unroll
      for (int i = 0; i < 4; ++i) aF[i] = ld16(swz(sA, wm*64u + (uint)i*16u + l15, (uint)kk*4u + quad));
      #pragma unroll
      for (int j = 0; j < 4; ++j) bF[j] = ld16(swz(sB, wn*64u + (uint)j*16u + l15, (uint)kk*4u + quad));
      #pragma unroll
      for (int i = 0; i < 4; ++i)
        #pragma unroll
        for (int j = 0; j < 4; ++j)
          acc[i][j] = __builtin_amdgcn_mfma_f32_16x16x32_f16(aF[i], bF[j], acc[i][j], 0, 0, 0);
    }
    __syncthreads();
  }
  int f32out = (MODE == 2) ? dtf[0] : 0;
  const float L2E = 1.44269504088896340736f;
  #pragma unroll
  for (int j = 0; j < 4; ++j){
    uint col = bn*128u + wn*64u + j*16u + l15;
    float bj = bias[col];
    #pragma unroll
    for (int i = 0; i < 4; ++i){
      uint row0 = bm*128u + wm*64u + i*16u + quad*4u;
      #pragma unroll
      for (int r = 0; r < 4; ++r){
        float val = acc[i][j][r] + bj;
        uint row = row0 + r;
        if (MODE == 0){
          ((ushort*)Cv)[(size_t)row*N + col] = f2h(val);
        } else if (MODE == 3){
          float v2 = (col >= 1024u) ? val * L2E : val;   // q pre-scaled by log2(e)
          ((ushort*)Cv)[(size_t)row*2048u + col] = f2h(v2);
        } else if (MODE == 4){
          // col = h*64+e ; row = b*512+s
          Vt[(size_t)(((row >> 9)*16u + (col >> 6))*64u + (col & 63u))*512u + (row & 511u)] = f2h(val);
        } else {
          if (f32out) ((float*)Cv)[(size_t)row*N + col] = val;
          else        ((ushort*)Cv)[(size_t)row*N + col] = f2bf(val);
        }
      }
    }
  }
}

// ---------------- fused attention ("transposed" causal, flash-style) ---------
// S[t,s] = K[t,:]·Q[s,:], keep s<=t, softmax over s, O[t,:] = sum_s P[t,s]V[s,:]
// kq: fp16 [16384][2048] (q pre-scaled by log2e); Vt: fp16 [(b*16+h)*64+e][512]
// S is already in log2 domain -> exp2 directly.
// LPT: heavy (large tt) blocks launch first; light blocks backfill the tail.
// UNCHANGED this round (measurement round — counters land in top-5 now).
__global__ __launch_bounds__(256, 4) void kattn(const ushort* __restrict__ kq,
                                                const ushort* __restrict__ Vt,
                                                ushort* __restrict__ Out){
  __shared__ ushort sQ[2][64*64];          // [s-local][d] swizzled   16 KB
  __shared__ ushort sV[2][64*64];          // [e][s-local] swizzled   16 KB
  __shared__ ushort pbuf[4][16*64];        // per-wave P (swizzled); K staging  8 KB
  uint tid = threadIdx.x, w = tid >> 6, lane = tid & 63u, quad = lane >> 4, l15 = lane & 15u;
  uint bh = blockIdx.x, tt = 7u - blockIdx.y;   // LPT: heavy tiles first
  uint b = bh >> 4, h = bh & 15u;
  uint t0 = tt*64u;
  const float MNEG = -1.0e30f;

  // stage K tile [t-local][d] into pbuf, Q0/V0 into buf 0 (all swizzled)
  stage64(kq + (size_t)(b*512u + t0)*2048u + h*64u, 2048u, (ushort*)pbuf, tid);
  stage64(kq + (size_t)(b*512u)*2048u + 1024u + h*64u, 2048u, sQ[0], tid);   // s0=0
  stage64(Vt + (size_t)(bh*64u)*512u, 512u, sV[0], tid);
  __syncthreads();

  f16x8 aK[2];  // K rows for this wave's 16 t's (wave-own pbuf rows)
  aK[0] = ld16(swz((const ushort*)pbuf, w*16u + l15, quad));
  aK[1] = ld16(swz((const ushort*)pbuf, w*16u + l15, 4u + quad));

  float m[4], l[4];
  f32x4 oacc[4];
  #pragma unroll
  for (int r = 0; r < 4; ++r){ m[r] = MNEG; l[r] = 0.f; }
  #pragma unroll
  for (int je = 0; je < 4; ++je) oacc[je] = (f32x4){0.f, 0.f, 0.f, 0.f};

  ushort* pw = (ushort*)pbuf + w*1024u;    // wave-private P region

  for (uint st = 0; st <= tt; ++st){
    uint cur = st & 1u;
    if (st) __syncthreads();               // staged bufs[cur] ready (vmcnt drained)
    if (st < tt){                          // prefetch st+1 with full-iter cover
      uint s1 = (st + 1u)*64u;
      stage64(kq + (size_t)(b*512u + s1)*2048u + 1024u + h*64u, 2048u, sQ[1u - cur], tid);
      stage64(Vt + (size_t)(bh*64u)*512u + s1, 512u, sV[1u - cur], tid);
    }
    f32x4 sacc[4];
    #pragma unroll
    for (int j = 0; j < 4; ++j){
      f16x8 bq0 = ld16(swz(sQ[cur], j*16u + l15, quad));
      f16x8 bq1 = ld16(swz(sQ[cur], j*16u + l15, 4u + quad));
      f32x4 s = (f32x4){0.f, 0.f, 0.f, 0.f};
      s = __builtin_amdgcn_mfma_f32_16x16x32_f16(aK[0], bq0, s, 0, 0, 0);
      s = __builtin_amdgcn_mfma_f32_16x16x32_f16(aK[1], bq1, s, 0, 0, 0);
      sacc[j] = s;
    }
    if (st == tt){  // diagonal tile: keep s<=t
      #pragma unroll
      for (int j = 0; j < 4; ++j)
        #pragma unroll
        for (int r = 0; r < 4; ++r)
          if (j*16u + l15 > w*16u + quad*4u + (uint)r) sacc[j][r] = MNEG;
    }
    float alpha[4];
    #pragma unroll
    for (int r = 0; r < 4; ++r){
      float v = fmaxf(fmaxf(sacc[0][r], sacc[1][r]), fmaxf(sacc[2][r], sacc[3][r]));
      v = fmaxf(v, __shfl_xor(v, 1));
      v = fmaxf(v, __shfl_xor(v, 2));
      v = fmaxf(v, __shfl_xor(v, 4));
      v = fmaxf(v, __shfl_xor(v, 8));
      float mn = fmaxf(m[r], v);
      alpha[r] = exp2f(m[r] - mn);         // already log2-domain
      m[r] = mn;
    }
    #pragma unroll
    for (int j = 0; j < 4; ++j)
      #pragma unroll
      for (int r = 0; r < 4; ++r)
        sacc[j][r] = exp2f(sacc[j][r] - m[r]);
    #pragma unroll
    for (int r = 0; r < 4; ++r){
      float s = sacc[0][r] + sacc[1][r] + sacc[2][r] + sacc[3][r];
      s += __shfl_xor(s, 1);
      s += __shfl_xor(s, 2);
      s += __shfl_xor(s, 4);
      s += __shfl_xor(s, 8);
      l[r] = l[r]*alpha[r] + s;
    }
    #pragma unroll
    for (int je = 0; je < 4; ++je)
      #pragma unroll
      for (int r = 0; r < 4; ++r)
        oacc[je][r] *= alpha[r];
    // P: C/D layout -> wave-private swizzled LDS -> A-operand frags (no barrier)
    #pragma unroll
    for (int j = 0; j < 4; ++j)
      #pragma unroll
      for (int r = 0; r < 4; ++r){
        uint t = quad*4u + (uint)r;
        pw[t*64u + (((j*2u + (l15 >> 3)) ^ (t & 7u))*8u) + (l15 & 7u)] = f2h(sacc[j][r]);
      }
    f16x8 aP0 = ld16(swz(pw, l15, quad));
    f16x8 aP1 = ld16(swz(pw, l15, 4u + quad));
    #pragma unroll
    for (int je = 0; je < 4; ++je){
      f16x8 bv0 = ld16(swz(sV[cur], je*16u + l15, quad));
      f16x8 bv1 = ld16(swz(sV[cur], je*16u + l15, 4u + quad));
      oacc[je] = __builtin_amdgcn_mfma_f32_16x16x32_f16(aP0, bv0, oacc[je], 0, 0, 0);
      oacc[je] = __builtin_amdgcn_mfma_f32_16x16x32_f16(aP1, bv1, oacc[je], 0, 0, 0);
    }
  }
  float inv[4];
  #pragma unroll
  for (int r = 0; r < 4; ++r) inv[r] = 1.0f / l[r];
  #pragma unroll
  for (int je = 0; je < 4; ++je){
    uint e = h*64u + je*16u + l15;
    #pragma unroll
    for (int r = 0; r < 4; ++r){
      uint t = t0 + w*16u + quad*4u + (uint)r;
      Out[(size_t)(b*512u + t)*1024u + e] = f2h(oacc[je][r]*inv[r]);
    }
  }
}

// ---------------- launcher ---------------------------------------------------

extern "C" void kernel_launch(void* const* d_in, const int* in_sizes, int n_in,
                              void* d_out, int out_size, void* d_ws, size_t ws_size,
                              hipStream_t stream){
  const void* x  = d_in[0];
  const void* Wi = d_in[1];
  const void* bi = d_in[2];
  const void* Wk = d_in[3];
  const void* bk = d_in[4];
  const void* Wq = d_in[5];
  const void* bq = d_in[6];
  const void* Wv = d_in[7];
  const void* bv = d_in[8];
  const void* Wo = d_in[9];
  const void* bo = d_in[10];
  char* ws = (char*)d_ws;

  const size_t MB = 1u << 20;
  int*    flag   = (int*)ws;
  float*  bi_f   = (float*)(ws + 4096);                  // 4 KB
  float*  bo_f   = (float*)(ws + 8192);                  // 4 KB
  float*  bqkv_f = (float*)(ws + 12288);                 // 12 KB
  ushort* WiT    = (ushort*)(ws + 32768);                // 2 MB  (fp16)
  ushort* WoT    = (ushort*)(ws + 32768 + 2*MB);         // 2 MB
  ushort* WqkvT  = (ushort*)(ws + 32768 + 4*MB);         // 6 MB
  ushort* xh     = (ushort*)(ws + 32768 + 10*MB);        // 32 MB (dead after GEMM0)
  ushort* kq     = (ushort*)(ws + 32768 + 10*MB);        // 64 MB (overlays xh)
  ushort* hbuf   = (ushort*)(ws + 32768 + 74*MB);        // 32 MB (h, then attn out)
  ushort* Vt     = (ushort*)(ws + 32768 + 106*MB);       // 32 MB -> total ~138 MB

  kdetect<<<dim3(1), dim3(256), 0, stream>>>((const uint*)Wi, flag);
  kbias<<<dim3(20), dim3(256), 0, stream>>>(bi, bo, bk, bq, bv, flag, bi_f, bo_f, bqkv_f);
  ktranspose<<<dim3(16, 16), dim3(256), 0, stream>>>(Wi, flag, WiT);
  ktranspose<<<dim3(16, 16), dim3(256), 0, stream>>>(Wo, flag, WoT);
  kqkvpack<<<dim3(48, 16), dim3(256), 0, stream>>>(Wk, Wq, Wv, flag, WqkvT);
  kcvt_x<<<dim3(8192), dim3(256), 0, stream>>>(x, flag, xh);

  kgemm<0><<<dim3(128, 8),  dim3(256), 0, stream>>>(xh,   WiT,           bi_f,          hbuf, nullptr, nullptr, NTOK, 1024, 1024);
  kgemm<3><<<dim3(128, 16), dim3(256), 0, stream>>>(hbuf, WqkvT,         bqkv_f,        kq,   nullptr, nullptr, NTOK, 2048, 1024);
  kgemm<4><<<dim3(128, 8),  dim3(256), 0, stream>>>(hbuf, WqkvT + (size_t)2048*1024, bqkv_f + 2048, nullptr, Vt, nullptr, NTOK, 1024, 1024);
  kattn<<<dim3(512, 8), dim3(256), 0, stream>>>(kq, Vt, hbuf);
  kgemm<2><<<dim3(128, 8),  dim3(256), 0, stream>>>(hbuf, WoT,           bo_f,          d_out, nullptr, flag,   NTOK, 1024, 1024);
}

// Round 5
// 443.064 us; speedup vs baseline: 1.1644x; 1.0203x over previous
//
#include <hip/hip_runtime.h>
#include <hip/hip_bf16.h>
#include <stdint.h>

// B=32, T=512, D=1024, H=16, HD=64
#define NTOK 16384

typedef _Float16 f16;
typedef f16   f16x8 __attribute__((ext_vector_type(8)));
typedef float f32x4 __attribute__((ext_vector_type(4)));

__device__ __forceinline__ float bf2f(ushort h){
  union { uint32_t u; float f; } v; v.u = ((uint32_t)h) << 16; return v.f;
}
__device__ __forceinline__ ushort f2bf(float f){
  union { float f; uint32_t u; } v; v.f = f;
  uint32_t u = v.u;
  return (ushort)((u + 0x7FFFu + ((u >> 16) & 1u)) >> 16);  // RNE
}
__device__ __forceinline__ ushort f2h(float f){          // fp32 -> fp16 bits (RNE)
  return __builtin_bit_cast(ushort, (f16)f);
}
__device__ __forceinline__ f16x8 ld16(const ushort* p){  // 8 fp16
  uint4 u = *(const uint4*)p;
  return __builtin_bit_cast(f16x8, u);
}
// dtype-flexible fp32 load: fp32 path direct, bf16 path converts
__device__ __forceinline__ float ldf(const void* p, size_t idx, int isf32){
  if (isf32) return ((const float*)p)[idx];
  return bf2f(((const ushort*)p)[idx]);
}

// XOR-swizzled [*][64] fp16 tile in LDS: element (row,col) lives at
//   row*64 + ((col>>3) ^ (row&7))*8 + (col&7)
// -> b128 fragment reads hit 8 distinct bank groups instead of serializing.
__device__ __forceinline__ const ushort* swz(const ushort* base, uint row, uint chunk){
  return base + (size_t)row*64u + (size_t)((chunk ^ (row & 7u))*8u);
}

// stage a 64x64 fp16 tile (row stride strideEl, 128B-contiguous rows) into
// swizzled LDS via global_load_lds width-16. Dest chunk is forced to be
// wave-uniform-base + lane*16B; we permute the SOURCE chunk instead (free).
__device__ __forceinline__ void stage64(const ushort* g, uint strideEl,
                                        ushort* ldsbase, uint tid){
  uint w = tid >> 6;
  #pragma unroll
  for (int i = 0; i < 2; ++i){
    uint lc  = i*256u + tid;               // dest chunk id (16B units)
    uint row = lc >> 3, cp = lc & 7u;
    uint c   = cp ^ (row & 7u);            // swizzled source chunk
    const ushort* gp = g + (size_t)row*strideEl + c*8u;
    ushort* lp = ldsbase + (size_t)(i*256u + w*64u)*8u;   // wave-uniform base
    __builtin_amdgcn_global_load_lds((const __attribute__((address_space(1))) void*)gp,
        (__attribute__((address_space(3))) void*)lp, 16, 0, 0);
  }
}

// stage a 128x64 fp16 tile (row stride K) into swizzled LDS (GEMM staging).
__device__ __forceinline__ void stage128(const ushort* g, int K,
                                         ushort* ldsbase, uint tid){
  uint w = tid >> 6;
  #pragma unroll
  for (int i = 0; i < 4; ++i){
    uint lc  = i*256u + tid;               // dest chunk id in [0,1024)
    uint row = lc >> 3, cp = lc & 7u;
    uint c   = cp ^ (row & 7u);            // swizzled source chunk
    const ushort* gp = g + (size_t)row*(size_t)K + c*8u;
    ushort* lp = ldsbase + (size_t)(i*256u + w*64u)*8u;   // wave-uniform base
    __builtin_amdgcn_global_load_lds((const __attribute__((address_space(1))) void*)gp,
        (__attribute__((address_space(3))) void*)lp, 16, 0, 0);
  }
}

// ---------------- merged preprocessing (one dispatch) -------------------------
// blocks [0,8192):      x -> canonical fp16 (8 elems/thread)
// blocks [8192,8704):   transpose Wi (256 blocks) then Wo (256 blocks)
// blocks [8704,9472):   qkv pack (768 blocks = 48 sh x 16 D0)
// blocks [9472,9492):   bias canonicalization (5120 elems); block 9472 writes flag
// Every block inline-recomputes the dtype vote (identical 256-value count over
// Wi's first 1KB, L2-hot broadcast) -> no cross-kernel flag dependency.
__global__ __launch_bounds__(256) void kprep(const void* __restrict__ x,
                                             const void* __restrict__ Wi, const void* __restrict__ Wo,
                                             const void* __restrict__ Wk, const void* __restrict__ Wq,
                                             const void* __restrict__ Wv,
                                             const void* __restrict__ bi, const void* __restrict__ bo,
                                             const void* __restrict__ bk, const void* __restrict__ bq,
                                             const void* __restrict__ bv,
                                             int* __restrict__ flag,
                                             float* __restrict__ bi_f, float* __restrict__ bo_f,
                                             float* __restrict__ bqkv_f,
                                             ushort* __restrict__ xh, ushort* __restrict__ WiT,
                                             ushort* __restrict__ WoT, ushort* __restrict__ WqkvT){
  __shared__ int cnt_s;
  __shared__ float tile[64][65];
  uint t = threadIdx.x, q = blockIdx.x;
  if (t == 0) cnt_s = 0;
  __syncthreads();
  {
    uint wv = ((const uint*)Wi)[t];
    uint e = (wv >> 7) & 0xFFu;
    if (e >= 100u && e <= 130u) atomicAdd(&cnt_s, 1);
  }
  __syncthreads();
  int f = (cnt_s < 128) ? 1 : 0;

  if (q < 8192u){
    size_t g = (size_t)(q*256u + t)*8u;
    ushort o[8];
    if (f){
      const float4* xf = (const float4*)((const float*)x + g);
      float4 a = xf[0], b2 = xf[1];
      o[0] = f2h(a.x);  o[1] = f2h(a.y);  o[2] = f2h(a.z);  o[3] = f2h(a.w);
      o[4] = f2h(b2.x); o[5] = f2h(b2.y); o[6] = f2h(b2.z); o[7] = f2h(b2.w);
    } else {
      uint4 u = *(const uint4*)((const ushort*)x + g);
      ushort s[8];
      *(uint4*)s = u;
      #pragma unroll
      for (int i = 0; i < 8; ++i) o[i] = f2h(bf2f(s[i]));
    }
    *(uint4*)(xh + g) = *(uint4*)o;
  } else if (q < 8704u){
    uint qq = q - 8192u;
    const void* in = (qq < 256u) ? Wi : Wo;
    ushort* out = (qq < 256u) ? WiT : WoT;
    uint qi = qq & 255u;
    uint R0 = (qi & 15u)*64u, C0 = (qi >> 4)*64u;
    #pragma unroll
    for (int i = 0; i < 16; ++i){
      uint id = i*256u + t, r = id >> 6, c = id & 63u;
      tile[r][c] = ldf(in, (size_t)(R0 + r)*1024u + C0 + c, f);
    }
    __syncthreads();
    #pragma unroll
    for (int i = 0; i < 16; ++i){
      uint id = i*256u + t, r = id >> 6, c = id & 63u;   // r = out-row (C-dim)
      out[(size_t)(C0 + r)*1024u + R0 + c] = f2h(tile[c][r]);
    }
  } else if (q < 9472u){
    uint qq = q - 8704u;                 // [0,768)
    uint sh = qq % 48u, D0 = (qq / 48u)*64u;
    uint sel = sh >> 4, h = sh & 15u;
    const void* W = (sel == 0) ? Wk : ((sel == 1) ? Wq : Wv);
    #pragma unroll
    for (int i = 0; i < 16; ++i){
      uint id = i*256u + t, r = id >> 6, c = id & 63u;   // r = d-local, c = e
      tile[r][c] = ldf(W, (size_t)h*65536u + (size_t)(D0 + r)*64u + c, f);
    }
    __syncthreads();
    #pragma unroll
    for (int i = 0; i < 16; ++i){
      uint id = i*256u + t, r = id >> 6, c = id & 63u;   // r = e, c = d-local
      WqkvT[(size_t)(sel*1024u + h*64u + r)*1024u + D0 + c] = f2h(tile[c][r]);
    }
  } else {
    uint id = (q - 9472u)*256u + t;      // [0,5120)
    if (id < 1024u)       bi_f[id]         = ldf(bi, id, f);
    else if (id < 2048u)  bo_f[id - 1024u] = ldf(bo, id - 1024u, f);
    else {
      uint j = id - 2048u;               // [0,3072): sel*1024 + (h*64+e)
      uint sel = j >> 10, i = j & 1023u;
      const void* src = (sel == 0) ? bk : ((sel == 1) ? bq : bv);
      bqkv_f[j] = ldf(src, i, f);
    }
    if (q == 9472u && t == 0) flag[0] = f;
  }
}

// ---------------- GEMM: C[M,N] = A[M,K] @ Bt[N,K]^T + bias (fp16) ------------
// m97 structure, BK=64 (32 MFMA per barrier-pair), XOR-swizzled [128][64] LDS
// tiles (source chunk pre-swizzle + swizzled read) -> conflict-free b128 reads.
// LDS 32 KB -> 4 blocks/CU with launch_bounds(256,4); each 1024-block dispatch
// runs in exactly ONE occupancy round.
// MODE 0: fp16 out [M,N].   MODE 2: final out, dtf picks f32/bf16.
// MODE 3: kq half-out [M,2048] at column base cb; q-half (cb!=0) pre-scaled by
//         log2(e) in f32 before the single f2h rounding (folds softmax base-2).
// MODE 4: V out, col = h*64+e in [0,1024) -> Vt scatter [(b,h,e)][s].
template<int MODE>
__global__ __launch_bounds__(256, 4) void kgemm(const ushort* __restrict__ A, const ushort* __restrict__ Bt,
                                                const float* __restrict__ bias, void* __restrict__ Cv,
                                                ushort* __restrict__ Vt, const int* __restrict__ dtf,
                                                int M, int N, int K, int cb){
  __shared__ ushort sA[128*64];   // 16 KB, swizzled
  __shared__ ushort sB[128*64];   // 16 KB, swizzled
  uint tid = threadIdx.x, w = tid >> 6, lane = tid & 63u, quad = lane >> 4, l15 = lane & 15u;
  uint bm = blockIdx.x, bn = blockIdx.y;
  uint wm = w >> 1, wn = w & 1u;
  f32x4 acc[4][4] = {};

  for (int k0 = 0; k0 < K; k0 += 64){
    stage128(A  + (size_t)(bm*128u)*(size_t)K + k0, K, sA, tid);
    stage128(Bt + (size_t)(bn*128u)*(size_t)K + k0, K, sB, tid);
    __syncthreads();
    #pragma unroll
    for (int kk = 0; kk < 2; ++kk){
      f16x8 aF[4], bF[4];
      #pragma unroll
      for (int i = 0; i < 4; ++i) aF[i] = ld16(swz(sA, wm*64u + (uint)i*16u + l15, (uint)kk*4u + quad));
      #pragma unroll
      for (int j = 0; j < 4; ++j) bF[j] = ld16(swz(sB, wn*64u + (uint)j*16u + l15, (uint)kk*4u + quad));
      #pragma unroll
      for (int i = 0; i < 4; ++i)
        #pragma unroll
        for (int j = 0; j < 4; ++j)
          acc[i][j] = __builtin_amdgcn_mfma_f32_16x16x32_f16(aF[i], bF[j], acc[i][j], 0, 0, 0);
    }
    __syncthreads();
  }
  int f32out = (MODE == 2) ? dtf[0] : 0;
  const float L2E = 1.44269504088896340736f;
  #pragma unroll
  for (int j = 0; j < 4; ++j){
    uint col = bn*128u + wn*64u + j*16u + l15;
    float bj = bias[col];
    #pragma unroll
    for (int i = 0; i < 4; ++i){
      uint row0 = bm*128u + wm*64u + i*16u + quad*4u;
      #pragma unroll
      for (int r = 0; r < 4; ++r){
        float val = acc[i][j][r] + bj;
        uint row = row0 + r;
        if (MODE == 0){
          ((ushort*)Cv)[(size_t)row*N + col] = f2h(val);
        } else if (MODE == 3){
          float v2 = cb ? val * L2E : val;   // q-half pre-scaled by log2(e)
          ((ushort*)Cv)[(size_t)row*2048u + (uint)cb + col] = f2h(v2);
        } else if (MODE == 4){
          // col = h*64+e ; row = b*512+s
          Vt[(size_t)(((row >> 9)*16u + (col >> 6))*64u + (col & 63u))*512u + (row & 511u)] = f2h(val);
        } else {
          if (f32out) ((float*)Cv)[(size_t)row*N + col] = val;
          else        ((ushort*)Cv)[(size_t)row*N + col] = f2bf(val);
        }
      }
    }
  }
}

// ---------------- fused attention ("transposed" causal, flash-style) ---------
// S[t,s] = K[t,:]·Q[s,:], keep s<=t, softmax over s, O[t,:] = sum_s P[t,s]V[s,:]
// kq: fp16 [16384][2048] (q pre-scaled by log2e); Vt: fp16 [(b*16+h)*64+e][512]
// S is already in log2 domain -> exp2 directly.
// LPT: heavy (large tt) blocks launch first; light blocks backfill the tail.
// UNCHANGED (measurement round — with all GEMMs at ~41-45 us this now surfaces
// in top-5 and we finally get its counters).
__global__ __launch_bounds__(256, 4) void kattn(const ushort* __restrict__ kq,
                                                const ushort* __restrict__ Vt,
                                                ushort* __restrict__ Out){
  __shared__ ushort sQ[2][64*64];          // [s-local][d] swizzled   16 KB
  __shared__ ushort sV[2][64*64];          // [e][s-local] swizzled   16 KB
  __shared__ ushort pbuf[4][16*64];        // per-wave P (swizzled); K staging  8 KB
  uint tid = threadIdx.x, w = tid >> 6, lane = tid & 63u, quad = lane >> 4, l15 = lane & 15u;
  uint bh = blockIdx.x, tt = 7u - blockIdx.y;   // LPT: heavy tiles first
  uint b = bh >> 4, h = bh & 15u;
  uint t0 = tt*64u;
  const float MNEG = -1.0e30f;

  // stage K tile [t-local][d] into pbuf, Q0/V0 into buf 0 (all swizzled)
  stage64(kq + (size_t)(b*512u + t0)*2048u + h*64u, 2048u, (ushort*)pbuf, tid);
  stage64(kq + (size_t)(b*512u)*2048u + 1024u + h*64u, 2048u, sQ[0], tid);   // s0=0
  stage64(Vt + (size_t)(bh*64u)*512u, 512u, sV[0], tid);
  __syncthreads();

  f16x8 aK[2];  // K rows for this wave's 16 t's (wave-own pbuf rows)
  aK[0] = ld16(swz((const ushort*)pbuf, w*16u + l15, quad));
  aK[1] = ld16(swz((const ushort*)pbuf, w*16u + l15, 4u + quad));

  float m[4], l[4];
  f32x4 oacc[4];
  #pragma unroll
  for (int r = 0; r < 4; ++r){ m[r] = MNEG; l[r] = 0.f; }
  #pragma unroll
  for (int je = 0; je < 4; ++je) oacc[je] = (f32x4){0.f, 0.f, 0.f, 0.f};

  ushort* pw = (ushort*)pbuf + w*1024u;    // wave-private P region

  for (uint st = 0; st <= tt; ++st){
    uint cur = st & 1u;
    if (st) __syncthreads();               // staged bufs[cur] ready (vmcnt drained)
    if (st < tt){                          // prefetch st+1 with full-iter cover
      uint s1 = (st + 1u)*64u;
      stage64(kq + (size_t)(b*512u + s1)*2048u + 1024u + h*64u, 2048u, sQ[1u - cur], tid);
      stage64(Vt + (size_t)(bh*64u)*512u + s1, 512u, sV[1u - cur], tid);
    }
    f32x4 sacc[4];
    #pragma unroll
    for (int j = 0; j < 4; ++j){
      f16x8 bq0 = ld16(swz(sQ[cur], j*16u + l15, quad));
      f16x8 bq1 = ld16(swz(sQ[cur], j*16u + l15, 4u + quad));
      f32x4 s = (f32x4){0.f, 0.f, 0.f, 0.f};
      s = __builtin_amdgcn_mfma_f32_16x16x32_f16(aK[0], bq0, s, 0, 0, 0);
      s = __builtin_amdgcn_mfma_f32_16x16x32_f16(aK[1], bq1, s, 0, 0, 0);
      sacc[j] = s;
    }
    if (st == tt){  // diagonal tile: keep s<=t
      #pragma unroll
      for (int j = 0; j < 4; ++j)
        #pragma unroll
        for (int r = 0; r < 4; ++r)
          if (j*16u + l15 > w*16u + quad*4u + (uint)r) sacc[j][r] = MNEG;
    }
    float alpha[4];
    #pragma unroll
    for (int r = 0; r < 4; ++r){
      float v = fmaxf(fmaxf(sacc[0][r], sacc[1][r]), fmaxf(sacc[2][r], sacc[3][r]));
      v = fmaxf(v, __shfl_xor(v, 1));
      v = fmaxf(v, __shfl_xor(v, 2));
      v = fmaxf(v, __shfl_xor(v, 4));
      v = fmaxf(v, __shfl_xor(v, 8));
      float mn = fmaxf(m[r], v);
      alpha[r] = exp2f(m[r] - mn);         // already log2-domain
      m[r] = mn;
    }
    #pragma unroll
    for (int j = 0; j < 4; ++j)
      #pragma unroll
      for (int r = 0; r < 4; ++r)
        sacc[j][r] = exp2f(sacc[j][r] - m[r]);
    #pragma unroll
    for (int r = 0; r < 4; ++r){
      float s = sacc[0][r] + sacc[1][r] + sacc[2][r] + sacc[3][r];
      s += __shfl_xor(s, 1);
      s += __shfl_xor(s, 2);
      s += __shfl_xor(s, 4);
      s += __shfl_xor(s, 8);
      l[r] = l[r]*alpha[r] + s;
    }
    #pragma unroll
    for (int je = 0; je < 4; ++je)
      #pragma unroll
      for (int r = 0; r < 4; ++r)
        oacc[je][r] *= alpha[r];
    // P: C/D layout -> wave-private swizzled LDS -> A-operand frags (no barrier)
    #pragma unroll
    for (int j = 0; j < 4; ++j)
      #pragma unroll
      for (int r = 0; r < 4; ++r){
        uint t = quad*4u + (uint)r;
        pw[t*64u + (((j*2u + (l15 >> 3)) ^ (t & 7u))*8u) + (l15 & 7u)] = f2h(sacc[j][r]);
      }
    f16x8 aP0 = ld16(swz(pw, l15, quad));
    f16x8 aP1 = ld16(swz(pw, l15, 4u + quad));
    #pragma unroll
    for (int je = 0; je < 4; ++je){
      f16x8 bv0 = ld16(swz(sV[cur], je*16u + l15, quad));
      f16x8 bv1 = ld16(swz(sV[cur], je*16u + l15, 4u + quad));
      oacc[je] = __builtin_amdgcn_mfma_f32_16x16x32_f16(aP0, bv0, oacc[je], 0, 0, 0);
      oacc[je] = __builtin_amdgcn_mfma_f32_16x16x32_f16(aP1, bv1, oacc[je], 0, 0, 0);
    }
  }
  float inv[4];
  #pragma unroll
  for (int r = 0; r < 4; ++r) inv[r] = 1.0f / l[r];
  #pragma unroll
  for (int je = 0; je < 4; ++je){
    uint e = h*64u + je*16u + l15;
    #pragma unroll
    for (int r = 0; r < 4; ++r){
      uint t = t0 + w*16u + quad*4u + (uint)r;
      Out[(size_t)(b*512u + t)*1024u + e] = f2h(oacc[je][r]*inv[r]);
    }
  }
}

// ---------------- launcher ---------------------------------------------------

extern "C" void kernel_launch(void* const* d_in, const int* in_sizes, int n_in,
                              void* d_out, int out_size, void* d_ws, size_t ws_size,
                              hipStream_t stream){
  const void* x  = d_in[0];
  const void* Wi = d_in[1];
  const void* bi = d_in[2];
  const void* Wk = d_in[3];
  const void* bk = d_in[4];
  const void* Wq = d_in[5];
  const void* bq = d_in[6];
  const void* Wv = d_in[7];
  const void* bv = d_in[8];
  const void* Wo = d_in[9];
  const void* bo = d_in[10];
  char* ws = (char*)d_ws;

  const size_t MB = 1u << 20;
  int*    flag   = (int*)ws;
  float*  bi_f   = (float*)(ws + 4096);                  // 4 KB
  float*  bo_f   = (float*)(ws + 8192);                  // 4 KB
  float*  bqkv_f = (float*)(ws + 12288);                 // 12 KB
  ushort* WiT    = (ushort*)(ws + 32768);                // 2 MB  (fp16)
  ushort* WoT    = (ushort*)(ws + 32768 + 2*MB);         // 2 MB
  ushort* WqkvT  = (ushort*)(ws + 32768 + 4*MB);         // 6 MB
  ushort* xh     = (ushort*)(ws + 32768 + 10*MB);        // 32 MB (dead after GEMM0)
  ushort* kq     = (ushort*)(ws + 32768 + 10*MB);        // 64 MB (overlays xh)
  ushort* hbuf   = (ushort*)(ws + 32768 + 74*MB);        // 32 MB (h, then attn out)
  ushort* Vt     = (ushort*)(ws + 32768 + 106*MB);       // 32 MB -> total ~138 MB

  kprep<<<dim3(9492), dim3(256), 0, stream>>>(x, Wi, Wo, Wk, Wq, Wv, bi, bo, bk, bq, bv,
                                              flag, bi_f, bo_f, bqkv_f, xh, WiT, WoT, WqkvT);

  kgemm<0><<<dim3(128, 8), dim3(256), 0, stream>>>(xh,   WiT, bi_f, hbuf, nullptr, nullptr, NTOK, 1024, 1024, 0);
  kgemm<3><<<dim3(128, 8), dim3(256), 0, stream>>>(hbuf, WqkvT,                      bqkv_f,        kq, nullptr, nullptr, NTOK, 1024, 1024, 0);
  kgemm<3><<<dim3(128, 8), dim3(256), 0, stream>>>(hbuf, WqkvT + (size_t)1024*1024,  bqkv_f + 1024, kq, nullptr, nullptr, NTOK, 1024, 1024, 1024);
  kgemm<4><<<dim3(128, 8), dim3(256), 0, stream>>>(hbuf, WqkvT + (size_t)2048*1024,  bqkv_f + 2048, nullptr, Vt, nullptr, NTOK, 1024, 1024, 0);
  kattn<<<dim3(512, 8), dim3(256), 0, stream>>>(kq, Vt, hbuf);
  kgemm<2><<<dim3(128, 8), dim3(256), 0, stream>>>(hbuf, WoT, bo_f, d_out, nullptr, flag, NTOK, 1024, 1024, 0);
}